// Round 1
// baseline (15385.461 us; speedup 1.0000x reference)
//
#include <hip/hip_runtime.h>
#include <hip/hip_bf16.h>

#define NDIM 100
#define HDIM 16
#define CDIM 20

// ---------------- degree / dinv ----------------

__global__ __launch_bounds__(256) void deg_kernel(const int* __restrict__ dst,
                                                  int* __restrict__ deg, int E) {
    int e = blockIdx.x * blockDim.x + threadIdx.x;
    if (e < E) atomicAdd(&deg[dst[e]], 1);
}

__global__ __launch_bounds__(256) void dinv_kernel(const int* __restrict__ deg,
                                                   float* __restrict__ dinv, int N) {
    int i = blockIdx.x * blockDim.x + threadIdx.x;
    if (i < N) dinv[i] = rsqrtf((float)(deg[i] + 1));  // +1 = self-loop
}

// ---------------- xw1 = x @ W1  ([N,100] @ [100,16]) ----------------
// 4 threads per node; thread q computes outputs [4q, 4q+4). W1 staged in LDS.

__global__ __launch_bounds__(256) void xw1_kernel(const float* __restrict__ x,
                                                  const float* __restrict__ W1,
                                                  float* __restrict__ xw1, int N) {
    __shared__ float Ws[NDIM * HDIM];  // 1600 floats, [k][j]
    for (int t = threadIdx.x; t < NDIM * HDIM; t += 256) Ws[t] = W1[t];
    __syncthreads();

    const int ln = threadIdx.x >> 2;          // 0..63
    const int q  = threadIdx.x & 3;           // output quad
    const int node = blockIdx.x * 64 + ln;
    if (node >= N) return;

    const float4* xr  = reinterpret_cast<const float4*>(x + (size_t)node * NDIM);
    const float4* Ws4 = reinterpret_cast<const float4*>(Ws);

    float4 acc = make_float4(0.f, 0.f, 0.f, 0.f);
#pragma unroll
    for (int kk = 0; kk < NDIM / 4; ++kk) {
        float4 xv = xr[kk];
        float xs[4] = {xv.x, xv.y, xv.z, xv.w};
#pragma unroll
        for (int c = 0; c < 4; ++c) {
            float4 w = Ws4[(kk * 4 + c) * 4 + q];  // W1[k][4q..4q+3]
            acc.x += xs[c] * w.x;
            acc.y += xs[c] * w.y;
            acc.z += xs[c] * w.z;
            acc.w += xs[c] * w.w;
        }
    }
    reinterpret_cast<float4*>(xw1 + (size_t)node * HDIM)[q] = acc;
}

// ---------------- edge scatter: acc[d] += dinv[s]*dinv[d] * xw[s] ----------------

template <int F>
__global__ __launch_bounds__(256) void edge_scatter(const int* __restrict__ src,
                                                    const int* __restrict__ dst,
                                                    const float* __restrict__ dinv,
                                                    const float* __restrict__ xw,
                                                    float* __restrict__ acc, int E) {
    int e = blockIdx.x * blockDim.x + threadIdx.x;
    if (e >= E) return;
    int s = src[e];
    int d = dst[e];
    float nrm = dinv[s] * dinv[d];
    const float4* xr = reinterpret_cast<const float4*>(xw + (size_t)s * F);
    float* ar = acc + (size_t)d * F;
#pragma unroll
    for (int c = 0; c < F / 4; ++c) {
        float4 v = xr[c];
        atomicAdd(ar + 4 * c + 0, nrm * v.x);
        atomicAdd(ar + 4 * c + 1, nrm * v.y);
        atomicAdd(ar + 4 * c + 2, nrm * v.z);
        atomicAdd(ar + 4 * c + 3, nrm * v.w);
    }
}

// ---------------- h = relu(acc1 + dinv^2*xw1 + b1); xw2 = h @ W2 ----------------

__global__ __launch_bounds__(256) void layer1_finish_xw2(const float* __restrict__ acc1,
                                                         const float* __restrict__ xw1,
                                                         const float* __restrict__ dinv,
                                                         const float* __restrict__ b1,
                                                         const float* __restrict__ W2,
                                                         float* __restrict__ xw2, int N) {
    __shared__ float W2t[CDIM * HDIM];  // [j][k] (transposed)
    __shared__ float b1s[HDIM];
    for (int t = threadIdx.x; t < CDIM * HDIM; t += 256) {
        int j = t / HDIM, k = t % HDIM;
        W2t[t] = W2[k * CDIM + j];
    }
    if (threadIdx.x < HDIM) b1s[threadIdx.x] = b1[threadIdx.x];
    __syncthreads();

    int n = blockIdx.x * blockDim.x + threadIdx.x;
    if (n >= N) return;

    float di = dinv[n];
    float d2 = di * di;
    float h[HDIM];
    const float4* a4 = reinterpret_cast<const float4*>(acc1 + (size_t)n * HDIM);
    const float4* x4 = reinterpret_cast<const float4*>(xw1 + (size_t)n * HDIM);
#pragma unroll
    for (int c = 0; c < HDIM / 4; ++c) {
        float4 a = a4[c];
        float4 xv = x4[c];
        float v;
        v = a.x + d2 * xv.x + b1s[4 * c + 0]; h[4 * c + 0] = v > 0.f ? v : 0.f;
        v = a.y + d2 * xv.y + b1s[4 * c + 1]; h[4 * c + 1] = v > 0.f ? v : 0.f;
        v = a.z + d2 * xv.z + b1s[4 * c + 2]; h[4 * c + 2] = v > 0.f ? v : 0.f;
        v = a.w + d2 * xv.w + b1s[4 * c + 3]; h[4 * c + 3] = v > 0.f ? v : 0.f;
    }

    float o[CDIM];
#pragma unroll
    for (int j = 0; j < CDIM; ++j) {
        const float4* w4 = reinterpret_cast<const float4*>(W2t + j * HDIM);
        float s = 0.f;
#pragma unroll
        for (int c = 0; c < HDIM / 4; ++c) {
            float4 w = w4[c];
            s += h[4 * c + 0] * w.x + h[4 * c + 1] * w.y +
                 h[4 * c + 2] * w.z + h[4 * c + 3] * w.w;
        }
        o[j] = s;
    }
    float4* out4 = reinterpret_cast<float4*>(xw2 + (size_t)n * CDIM);
#pragma unroll
    for (int c = 0; c < CDIM / 4; ++c)
        out4[c] = make_float4(o[4 * c], o[4 * c + 1], o[4 * c + 2], o[4 * c + 3]);
}

// ---------------- out = log_softmax(acc2 + dinv^2*xw2 + b2) ----------------

__global__ __launch_bounds__(256) void final_kernel(const float* __restrict__ acc2,
                                                    const float* __restrict__ xw2,
                                                    const float* __restrict__ dinv,
                                                    const float* __restrict__ b2,
                                                    float* __restrict__ out, int N) {
    __shared__ float b2s[CDIM];
    if (threadIdx.x < CDIM) b2s[threadIdx.x] = b2[threadIdx.x];
    __syncthreads();

    int n = blockIdx.x * blockDim.x + threadIdx.x;
    if (n >= N) return;

    float di = dinv[n];
    float d2 = di * di;
    float t[CDIM];
    const float4* a4 = reinterpret_cast<const float4*>(acc2 + (size_t)n * CDIM);
    const float4* x4 = reinterpret_cast<const float4*>(xw2 + (size_t)n * CDIM);
#pragma unroll
    for (int c = 0; c < CDIM / 4; ++c) {
        float4 a = a4[c];
        float4 xv = x4[c];
        t[4 * c + 0] = a.x + d2 * xv.x + b2s[4 * c + 0];
        t[4 * c + 1] = a.y + d2 * xv.y + b2s[4 * c + 1];
        t[4 * c + 2] = a.z + d2 * xv.z + b2s[4 * c + 2];
        t[4 * c + 3] = a.w + d2 * xv.w + b2s[4 * c + 3];
    }
    float m = t[0];
#pragma unroll
    for (int j = 1; j < CDIM; ++j) m = fmaxf(m, t[j]);
    float s = 0.f;
#pragma unroll
    for (int j = 0; j < CDIM; ++j) s += __expf(t[j] - m);
    float l = __logf(s);

    float4* o4 = reinterpret_cast<float4*>(out + (size_t)n * CDIM);
#pragma unroll
    for (int c = 0; c < CDIM / 4; ++c)
        o4[c] = make_float4(t[4 * c + 0] - m - l, t[4 * c + 1] - m - l,
                            t[4 * c + 2] - m - l, t[4 * c + 3] - m - l);
}

// ---------------- launch ----------------

extern "C" void kernel_launch(void* const* d_in, const int* in_sizes, int n_in,
                              void* d_out, int out_size, void* d_ws, size_t ws_size,
                              hipStream_t stream) {
    const float* x  = (const float*)d_in[0];
    const int* edge = (const int*)d_in[1];   // [2, E] int32
    const float* W1 = (const float*)d_in[2];
    const float* b1 = (const float*)d_in[3];
    const float* W2 = (const float*)d_in[4];
    const float* b2 = (const float*)d_in[5];
    float* out = (float*)d_out;

    const int N = in_sizes[0] / NDIM;   // 500000
    const int E = in_sizes[1] / 2;      // 8000000
    const int* src = edge;
    const int* dst = edge + E;

    char* ws = (char*)d_ws;
    size_t off = 0;
    int*   deg  = (int*)(ws + off);   off += (size_t)N * 4;
    float* dinv = (float*)(ws + off); off += (size_t)N * 4;
    float* xw1  = (float*)(ws + off); off += (size_t)N * HDIM * 4;
    float* acc1 = (float*)(ws + off); off += (size_t)N * HDIM * 4;
    float* xw2  = (float*)(ws + off); off += (size_t)N * CDIM * 4;
    float* acc2 = (float*)(ws + off); off += (size_t)N * CDIM * 4;

    hipMemsetAsync(deg,  0, (size_t)N * 4, stream);
    hipMemsetAsync(acc1, 0, (size_t)N * HDIM * 4, stream);
    hipMemsetAsync(acc2, 0, (size_t)N * CDIM * 4, stream);

    const int tb = 256;
    deg_kernel<<<(E + tb - 1) / tb, tb, 0, stream>>>(dst, deg, E);
    dinv_kernel<<<(N + tb - 1) / tb, tb, 0, stream>>>(deg, dinv, N);
    xw1_kernel<<<(N + 63) / 64, tb, 0, stream>>>(x, W1, xw1, N);
    edge_scatter<HDIM><<<(E + tb - 1) / tb, tb, 0, stream>>>(src, dst, dinv, xw1, acc1, E);
    layer1_finish_xw2<<<(N + tb - 1) / tb, tb, 0, stream>>>(acc1, xw1, dinv, b1, W2, xw2, N);
    edge_scatter<CDIM><<<(E + tb - 1) / tb, tb, 0, stream>>>(src, dst, dinv, xw2, acc2, E);
    final_kernel<<<(N + tb - 1) / tb, tb, 0, stream>>>(acc2, xw2, dinv, b2, out, N);
}

// Round 2
// 1947.417 us; speedup vs baseline: 7.9004x; 7.9004x over previous
//
#include <hip/hip_runtime.h>
#include <hip/hip_bf16.h>

#define NDIM 100
#define HDIM 16
#define CDIM 20

// ---------------- degree histogram over dst ----------------

__global__ __launch_bounds__(256) void deg_kernel(const int* __restrict__ dst,
                                                  int* __restrict__ deg, int E) {
    int e = blockIdx.x * blockDim.x + threadIdx.x;
    if (e < E) atomicAdd(&deg[dst[e]], 1);
}

__global__ __launch_bounds__(256) void dinv_kernel(const int* __restrict__ deg,
                                                   float* __restrict__ dinv, int N) {
    int i = blockIdx.x * blockDim.x + threadIdx.x;
    if (i < N) dinv[i] = rsqrtf((float)(deg[i] + 1));  // +1 = self-loop
}

// ---------------- exclusive prefix sum (3 kernels) ----------------
// k1: per-block inclusive scan of deg -> cursor; block total -> bsum[b]

__global__ __launch_bounds__(256) void scan_k1(const int* __restrict__ deg,
                                               int* __restrict__ cursor,
                                               int* __restrict__ bsum, int N) {
    __shared__ int tmp[256];
    int t = threadIdx.x;
    int i = blockIdx.x * 256 + t;
    int v = (i < N) ? deg[i] : 0;
    tmp[t] = v;
    __syncthreads();
    for (int off = 1; off < 256; off <<= 1) {
        int add = (t >= off) ? tmp[t - off] : 0;
        __syncthreads();
        tmp[t] += add;
        __syncthreads();
    }
    if (i < N) cursor[i] = tmp[t];           // inclusive within block
    if (t == 255) bsum[blockIdx.x] = tmp[255];
}

// k2: exclusive scan of bsum (nb <= 2048), single block of 256, 8 elems/thread

__global__ __launch_bounds__(256) void scan_k2(int* __restrict__ bsum, int nb) {
    __shared__ int part[256];
    int t = threadIdx.x;
    int base = t * 8;
    int loc[8];
    int s = 0;
#pragma unroll
    for (int k = 0; k < 8; ++k) {
        int idx = base + k;
        loc[k] = (idx < nb) ? bsum[idx] : 0;
        s += loc[k];
    }
    part[t] = s;
    __syncthreads();
    for (int off = 1; off < 256; off <<= 1) {
        int add = (t >= off) ? part[t - off] : 0;
        __syncthreads();
        part[t] += add;
        __syncthreads();
    }
    int run = (t > 0) ? part[t - 1] : 0;     // exclusive prefix of this chunk
#pragma unroll
    for (int k = 0; k < 8; ++k) {
        int idx = base + k;
        if (idx < nb) bsum[idx] = run;
        run += loc[k];
    }
}

// k3: cursor[i] = global exclusive start = (incl - deg) + block offset

__global__ __launch_bounds__(256) void scan_k3(const int* __restrict__ deg,
                                               int* __restrict__ cursor,
                                               const int* __restrict__ bsum, int N) {
    int i = blockIdx.x * 256 + threadIdx.x;
    if (i < N) cursor[i] = cursor[i] - deg[i] + bsum[blockIdx.x];
}

// ---------------- counting-sort scatter: esrc bucketed by dst ----------------
// After this, cursor[i] == end of segment i; start = cursor[i] - deg[i].

__global__ __launch_bounds__(256) void scatter_build(const int* __restrict__ src,
                                                     const int* __restrict__ dst,
                                                     int* __restrict__ cursor,
                                                     int* __restrict__ esrc, int E) {
    int e = blockIdx.x * blockDim.x + threadIdx.x;
    if (e >= E) return;
    int d = dst[e];
    int pos = atomicAdd(&cursor[d], 1);
    esrc[pos] = src[e];
}

// ---------------- xw1 = x @ W1  ([N,100] @ [100,16]) ----------------

__global__ __launch_bounds__(256) void xw1_kernel(const float* __restrict__ x,
                                                  const float* __restrict__ W1,
                                                  float* __restrict__ xw1, int N) {
    __shared__ float Ws[NDIM * HDIM];  // [k][j]
    for (int t = threadIdx.x; t < NDIM * HDIM; t += 256) Ws[t] = W1[t];
    __syncthreads();

    const int ln = threadIdx.x >> 2;
    const int q  = threadIdx.x & 3;
    const int node = blockIdx.x * 64 + ln;
    if (node >= N) return;

    const float4* xr  = reinterpret_cast<const float4*>(x + (size_t)node * NDIM);
    const float4* Ws4 = reinterpret_cast<const float4*>(Ws);

    float4 acc = make_float4(0.f, 0.f, 0.f, 0.f);
#pragma unroll
    for (int kk = 0; kk < NDIM / 4; ++kk) {
        float4 xv = xr[kk];
        float xs[4] = {xv.x, xv.y, xv.z, xv.w};
#pragma unroll
        for (int c = 0; c < 4; ++c) {
            float4 w = Ws4[(kk * 4 + c) * 4 + q];
            acc.x += xs[c] * w.x;
            acc.y += xs[c] * w.y;
            acc.z += xs[c] * w.z;
            acc.w += xs[c] * w.w;
        }
    }
    reinterpret_cast<float4*>(xw1 + (size_t)node * HDIM)[q] = acc;
}

// ---------------- layer-1 gather-reduce + epilogue: h = relu(...) ----------------
// 16 lanes per node, 16 nodes per 256-thread block. Lane f owns feature f.

__global__ __launch_bounds__(256) void gather1(const int* __restrict__ esrc,
                                               const int* __restrict__ cursor,
                                               const int* __restrict__ deg,
                                               const float* __restrict__ dinv,
                                               const float* __restrict__ xw1,
                                               const float* __restrict__ b1,
                                               float* __restrict__ h, int N) {
    int g = threadIdx.x >> 4;
    int f = threadIdx.x & 15;
    int n = blockIdx.x * 16 + g;
    if (n >= N) return;

    int end = cursor[n];
    int len = deg[n];
    int start = end - len;
    float dn = dinv[n];

    float acc = 0.f;
    for (int j = start; j < end; ++j) {
        int s = esrc[j];                          // broadcast within group
        acc += dinv[s] * xw1[(size_t)s * HDIM + f];  // 16-lane coalesced 64B gather
    }
    float v = dn * acc + dn * dn * xw1[(size_t)n * HDIM + f] + b1[f];
    h[(size_t)n * HDIM + f] = fmaxf(v, 0.f);
}

// ---------------- xw2 = h @ W2  ([N,16] @ [16,20]) ----------------

__global__ __launch_bounds__(256) void xw2_kernel(const float* __restrict__ h,
                                                  const float* __restrict__ W2,
                                                  float* __restrict__ xw2, int N) {
    __shared__ float W2t[CDIM * HDIM];  // [j][k]
    for (int t = threadIdx.x; t < CDIM * HDIM; t += 256) {
        int j = t / HDIM, k = t % HDIM;
        W2t[t] = W2[k * CDIM + j];
    }
    __syncthreads();

    int n = blockIdx.x * blockDim.x + threadIdx.x;
    if (n >= N) return;

    float hv[HDIM];
    const float4* h4 = reinterpret_cast<const float4*>(h + (size_t)n * HDIM);
#pragma unroll
    for (int c = 0; c < HDIM / 4; ++c) {
        float4 a = h4[c];
        hv[4 * c + 0] = a.x; hv[4 * c + 1] = a.y;
        hv[4 * c + 2] = a.z; hv[4 * c + 3] = a.w;
    }
    float o[CDIM];
#pragma unroll
    for (int j = 0; j < CDIM; ++j) {
        const float4* w4 = reinterpret_cast<const float4*>(W2t + j * HDIM);
        float s = 0.f;
#pragma unroll
        for (int c = 0; c < HDIM / 4; ++c) {
            float4 w = w4[c];
            s += hv[4 * c + 0] * w.x + hv[4 * c + 1] * w.y +
                 hv[4 * c + 2] * w.z + hv[4 * c + 3] * w.w;
        }
        o[j] = s;
    }
    float4* out4 = reinterpret_cast<float4*>(xw2 + (size_t)n * CDIM);
#pragma unroll
    for (int c = 0; c < CDIM / 4; ++c)
        out4[c] = make_float4(o[4 * c], o[4 * c + 1], o[4 * c + 2], o[4 * c + 3]);
}

// ---------------- layer-2 gather-reduce: logits -> d_out ----------------
// 32 lanes per node, 8 nodes per block; lanes 0..19 own features.

__global__ __launch_bounds__(256) void gather2(const int* __restrict__ esrc,
                                               const int* __restrict__ cursor,
                                               const int* __restrict__ deg,
                                               const float* __restrict__ dinv,
                                               const float* __restrict__ xw2,
                                               const float* __restrict__ b2,
                                               float* __restrict__ logits, int N) {
    int g = threadIdx.x >> 5;
    int f = threadIdx.x & 31;
    int n = blockIdx.x * 8 + g;
    if (n >= N) return;

    int end = cursor[n];
    int len = deg[n];
    int start = end - len;
    float dn = dinv[n];

    float acc = 0.f;
    for (int j = start; j < end; ++j) {
        int s = esrc[j];
        float ds = dinv[s];
        if (f < CDIM) acc += ds * xw2[(size_t)s * CDIM + f];
    }
    if (f < CDIM) {
        float t = dn * acc + dn * dn * xw2[(size_t)n * CDIM + f] + b2[f];
        logits[(size_t)n * CDIM + f] = t;
    }
}

// ---------------- in-place log_softmax over d_out rows ----------------

__global__ __launch_bounds__(256) void logsoftmax_kernel(float* __restrict__ out, int N) {
    int n = blockIdx.x * blockDim.x + threadIdx.x;
    if (n >= N) return;
    float t[CDIM];
    float4* o4 = reinterpret_cast<float4*>(out + (size_t)n * CDIM);
#pragma unroll
    for (int c = 0; c < CDIM / 4; ++c) {
        float4 a = o4[c];
        t[4 * c + 0] = a.x; t[4 * c + 1] = a.y;
        t[4 * c + 2] = a.z; t[4 * c + 3] = a.w;
    }
    float m = t[0];
#pragma unroll
    for (int j = 1; j < CDIM; ++j) m = fmaxf(m, t[j]);
    float s = 0.f;
#pragma unroll
    for (int j = 0; j < CDIM; ++j) s += __expf(t[j] - m);
    float l = __logf(s);
#pragma unroll
    for (int c = 0; c < CDIM / 4; ++c)
        o4[c] = make_float4(t[4 * c + 0] - m - l, t[4 * c + 1] - m - l,
                            t[4 * c + 2] - m - l, t[4 * c + 3] - m - l);
}

// ---------------- launch ----------------

extern "C" void kernel_launch(void* const* d_in, const int* in_sizes, int n_in,
                              void* d_out, int out_size, void* d_ws, size_t ws_size,
                              hipStream_t stream) {
    const float* x  = (const float*)d_in[0];
    const int* edge = (const int*)d_in[1];   // [2, E] int32
    const float* W1 = (const float*)d_in[2];
    const float* b1 = (const float*)d_in[3];
    const float* W2 = (const float*)d_in[4];
    const float* b2 = (const float*)d_in[5];
    float* out = (float*)d_out;

    const int N = in_sizes[0] / NDIM;   // 500000
    const int E = in_sizes[1] / 2;      // 8000000
    const int* src = edge;
    const int* dst = edge + E;

    const int tb = 256;
    const int nbN = (N + tb - 1) / tb;  // 1954 blocks for N

    char* ws = (char*)d_ws;
    size_t off = 0;
    int*   deg    = (int*)(ws + off);   off += (size_t)N * 4;
    int*   cursor = (int*)(ws + off);   off += (size_t)N * 4;
    int*   bsum   = (int*)(ws + off);   off += 2048 * 4;
    float* dinv   = (float*)(ws + off); off += (size_t)N * 4;
    float* xw1    = (float*)(ws + off); off += (size_t)N * HDIM * 4;
    float* h      = (float*)(ws + off); off += (size_t)N * HDIM * 4;
    float* xw2    = (float*)(ws + off); off += (size_t)N * CDIM * 4;
    int*   esrc   = (int*)(ws + off);   off += (size_t)E * 4;

    hipMemsetAsync(deg, 0, (size_t)N * 4, stream);

    // degree + dinv
    deg_kernel<<<(E + tb - 1) / tb, tb, 0, stream>>>(dst, deg, E);
    dinv_kernel<<<nbN, tb, 0, stream>>>(deg, dinv, N);

    // CSR build: exclusive scan + counting-sort
    scan_k1<<<nbN, tb, 0, stream>>>(deg, cursor, bsum, N);
    scan_k2<<<1, tb, 0, stream>>>(bsum, nbN);
    scan_k3<<<nbN, tb, 0, stream>>>(deg, cursor, bsum, N);
    scatter_build<<<(E + tb - 1) / tb, tb, 0, stream>>>(src, dst, cursor, esrc, E);

    // dense matmul xw1 (overlappable with CSR build in principle; serial on stream)
    xw1_kernel<<<(N + 63) / 64, tb, 0, stream>>>(x, W1, xw1, N);

    // layer 1: gather-reduce + relu epilogue
    gather1<<<(N + 15) / 16, tb, 0, stream>>>(esrc, cursor, deg, dinv, xw1, b1, h, N);

    // dense matmul xw2
    xw2_kernel<<<nbN, tb, 0, stream>>>(h, W2, xw2, N);

    // layer 2: gather-reduce -> logits in d_out
    gather2<<<(N + 7) / 8, tb, 0, stream>>>(esrc, cursor, deg, dinv, xw2, b2, out, N);

    // in-place log_softmax
    logsoftmax_kernel<<<nbN, tb, 0, stream>>>(out, N);
}